// Round 1
// baseline (2052.701 us; speedup 1.0000x reference)
//
#include <hip/hip_runtime.h>
#include <math.h>

#define NH    114    // rows per image (height)
#define WIN   130    // input width
#define WO1   66     // conv1 out width
#define WO2   37     // conv2 out width
#define C1    5
#define C2    10
#define C3    20
#define K1    65
#define K2    30
#define K3    37
#define NN    114    // graph nodes per batch

__device__ __forceinline__ float elu_f(float x) { return x > 0.f ? x : expm1f(x); }

// ---------------- Kernel 1: conv pipeline, one wave per (b,h) row ----------------
__global__ __launch_bounds__(256) void conv_rows_kernel(
    const float* __restrict__ x,
    const float* __restrict__ w1, const float* __restrict__ b1,
    const float* __restrict__ g1, const float* __restrict__ be1,
    const float* __restrict__ w2, const float* __restrict__ b2,
    const float* __restrict__ g2, const float* __restrict__ be2,
    const float* __restrict__ w3, const float* __restrict__ b3,
    const float* __restrict__ g3, const float* __restrict__ be3,
    float* __restrict__ feats, int nrows)
{
    __shared__ float sw1[K1 * C1];            // 325
    __shared__ float sw2[K2 * C1 * C2];       // 1500
    __shared__ float sw3[K3 * C2 * C3];       // 7400
    __shared__ float sxin[4][WIN];
    __shared__ float ss1[4][WO1 * C1];        // 330
    __shared__ float ss2[4][WO2 * C2];        // 370
    __shared__ float st[4][C3];

    const int tid = threadIdx.x;
    for (int i = tid; i < K1 * C1; i += 256) sw1[i] = w1[i];
    for (int i = tid; i < K2 * C1 * C2; i += 256) sw2[i] = w2[i];
    for (int i = tid; i < K3 * C2 * C3; i += 256) sw3[i] = w3[i];

    const int wave = tid >> 6;
    const int lane = tid & 63;
    const int row  = blockIdx.x * 4 + wave;
    const bool rv  = row < nrows;

    if (rv) {
        const float* xr = x + (size_t)row * WIN;
        sxin[wave][lane]      = xr[lane];
        sxin[wave][64 + lane] = xr[64 + lane];
        if (lane < WIN - 128) sxin[wave][128 + lane] = xr[128 + lane];
    }
    __syncthreads();

    // ---- conv1 + LN + ELU ----
    if (rv) {
        float rb[C1], rg[C1], rbe[C1];
        #pragma unroll
        for (int c = 0; c < C1; ++c) { rb[c] = b1[c]; rg[c] = g1[c]; rbe[c] = be1[c]; }
        for (int w = lane; w < WO1; w += 64) {
            float acc[C1];
            #pragma unroll
            for (int c = 0; c < C1; ++c) acc[c] = rb[c];
            for (int k = 0; k < K1; ++k) {
                float xv = sxin[wave][w + k];
                #pragma unroll
                for (int c = 0; c < C1; ++c) acc[c] += xv * sw1[k * C1 + c];
            }
            float m = 0.f;
            #pragma unroll
            for (int c = 0; c < C1; ++c) m += acc[c];
            m *= (1.f / C1);
            float v = 0.f;
            #pragma unroll
            for (int c = 0; c < C1; ++c) { float d = acc[c] - m; v += d * d; }
            v *= (1.f / C1);
            float inv = rsqrtf(v + 1e-3f);
            #pragma unroll
            for (int c = 0; c < C1; ++c)
                ss1[wave][w * C1 + c] = elu_f((acc[c] - m) * inv * rg[c] + rbe[c]);
        }
    }
    __syncthreads();

    // ---- conv2 + LN + ELU ----
    if (rv && lane < WO2) {
        float acc[C2];
        #pragma unroll
        for (int o = 0; o < C2; ++o) acc[o] = b2[o];
        for (int k = 0; k < K2; ++k) {
            #pragma unroll
            for (int i = 0; i < C1; ++i) {
                float v = ss1[wave][(lane + k) * C1 + i];
                const float* wp = &sw2[(k * C1 + i) * C2];
                #pragma unroll
                for (int o = 0; o < C2; ++o) acc[o] += v * wp[o];
            }
        }
        float m = 0.f;
        #pragma unroll
        for (int o = 0; o < C2; ++o) m += acc[o];
        m *= (1.f / C2);
        float v = 0.f;
        #pragma unroll
        for (int o = 0; o < C2; ++o) { float d = acc[o] - m; v += d * d; }
        v *= (1.f / C2);
        float inv = rsqrtf(v + 1e-3f);
        #pragma unroll
        for (int o = 0; o < C2; ++o)
            ss2[wave][lane * C2 + o] = elu_f((acc[o] - m) * inv * g2[o] + be2[o]);
    }
    __syncthreads();

    // ---- conv3 (raw accumulators) ----
    if (rv && lane < C3) {
        float acc = b3[lane];
        for (int j = 0; j < K3 * C2; ++j)
            acc += ss2[wave][j] * sw3[j * C3 + lane];
        st[wave][lane] = acc;
    }
    __syncthreads();

    // ---- LN3 + ELU -> feats ----
    if (rv && lane < C3) {
        float m = 0.f;
        #pragma unroll
        for (int c = 0; c < C3; ++c) m += st[wave][c];
        m *= (1.f / C3);
        float v = 0.f;
        #pragma unroll
        for (int c = 0; c < C3; ++c) { float d = st[wave][c] - m; v += d * d; }
        v *= (1.f / C3);
        float inv = rsqrtf(v + 1e-3f);
        feats[(size_t)row * C3 + lane] =
            elu_f((st[wave][lane] - m) * inv * g3[lane] + be3[lane]);
    }
}

// ---------------- Kernel 2: per-batch graph block ----------------
__global__ __launch_bounds__(256) void graph_kernel(
    const float* __restrict__ feats,     // [B,114,20]
    const float* __restrict__ agent_w, const float* __restrict__ agent_b,
    const float* __restrict__ g1w, const float* __restrict__ g1b,
    const float* __restrict__ g2w, const float* __restrict__ g2b,
    const float* __restrict__ dw, const float* __restrict__ db,
    const int* __restrict__ rlp,
    float* __restrict__ out)
{
    __shared__ float sfe[NN * C3];   // feats -> later h1 [0..1140), h2 [1140..1710)
    __shared__ float sfc[NN * C3];   // fc    -> later t1 [0..1140), t2 [1140..1710)
    __shared__ float sA[NN * NN];    // dist -> A2 -> L (in place)
    __shared__ float snrm[NN], sidx[NN], sdv[NN];
    __shared__ float red[256];
    __shared__ float ssigma;
    __shared__ float sfeat[10];
    __shared__ float sg1[C3 * C2], sg1b[C2], sg2[C2 * C1], sg2b[C1], sdw[20], sdb[2];

    const int tid = threadIdx.x;
    const int b = blockIdx.x;
    const float* F = feats + (size_t)b * (NN * C3);
    const int rl = rlp[0];

    if (tid < C3 * C2) sg1[tid] = g1w[tid];
    if (tid < C2) sg1b[tid] = g1b[tid];
    if (tid < C2 * C1) sg2[tid] = g2w[tid];
    if (tid < C1) sg2b[tid] = g2b[tid];
    if (tid < 20) sdw[tid] = dw[tid];
    if (tid < 2) sdb[tid] = db[tid];

    // Step 1: load feats rows; fc, nrm, index
    for (int n = tid; n < NN; n += 256) {
        float f[C3];
        float m = 0.f;
        #pragma unroll
        for (int d = 0; d < C3; ++d) { f[d] = F[n * C3 + d]; m += f[d]; }
        m *= (1.f / C3);
        float nr = 0.f, ag = 0.f;
        #pragma unroll
        for (int d = 0; d < C3; ++d) {
            sfe[n * C3 + d] = f[d];
            float c = f[d] - m;
            sfc[n * C3 + d] = c;
            nr += c * c;
            ag += f[d] * agent_w[d];
        }
        snrm[n] = sqrtf(nr);
        sidx[n] = rl ? (1.f / (1.f + expf(-(ag + agent_b[0])))) : 1.f;
    }
    __syncthreads();

    // Step 2: dist + sigma partial sums
    float psum = 0.f;
    for (int e = tid; e < NN * NN; e += 256) {
        int n = e / NN, m = e - n * NN;
        float dot = 0.f;
        #pragma unroll
        for (int d = 0; d < C3; ++d) dot += sfc[n * C3 + d] * sfc[m * C3 + d];
        float corr = dot / (snrm[n] * snrm[m]);
        float dist = (n == m) ? 0.f : (1.f - corr);
        sA[e] = dist;
        psum += dist;
    }
    red[tid] = psum;
    __syncthreads();
    for (int s = 128; s > 0; s >>= 1) {
        if (tid < s) red[tid] += red[tid + s];
        __syncthreads();
    }
    if (tid == 0) ssigma = red[0] / (float)(NN * NN);
    __syncthreads();

    // Step 3: A2 = idx[n]*idx[m]*exp(-dist^2/(2 sigma^2))
    const float sig = ssigma;
    const float inv2s2 = 1.f / (2.f * sig * sig);
    for (int e = tid; e < NN * NN; e += 256) {
        int n = e / NN, m = e - n * NN;
        float dist = sA[e];
        sA[e] = sidx[n] * sidx[m] * expf(-dist * dist * inv2s2);
    }
    __syncthreads();

    // Step 4: d = 1/sqrt(rowsum), inf->0
    for (int n = tid; n < NN; n += 256) {
        float s = 0.f;
        for (int m = 0; m < NN; ++m) s += sA[n * NN + m];
        float dv = rsqrtf(s);
        if (isinf(dv)) dv = 0.f;
        sdv[n] = dv;
    }
    __syncthreads();

    // Step 5: L = d A d
    for (int e = tid; e < NN * NN; e += 256) {
        int n = e / NN, m = e - n * NN;
        sA[e] *= sdv[n] * sdv[m];
    }
    __syncthreads();

    // Step 6: t1 = (feats*index) @ g1w + g1b  -> sfc[0..1140)
    for (int e = tid; e < NN * C2; e += 256) {
        int n = e / C2, o = e - n * C2;
        float acc = 0.f;
        #pragma unroll
        for (int d = 0; d < C3; ++d) acc += sfe[n * C3 + d] * sg1[d * C2 + o];
        sfc[e] = acc * sidx[n] + sg1b[o];
    }
    __syncthreads();

    // Step 7: h1 = elu(L @ t1) -> sfe[0..1140)
    for (int e = tid; e < NN * C2; e += 256) {
        int n = e / C2, o = e - n * C2;
        float acc = 0.f;
        for (int m = 0; m < NN; ++m) acc += sA[n * NN + m] * sfc[m * C2 + o];
        sfe[e] = elu_f(acc);
    }
    __syncthreads();

    // Step 8: t2 = h1 @ g2w + g2b -> sfc[1140..1710)
    for (int e = tid; e < NN * C1; e += 256) {
        int n = e / C1, c = e - n * C1;
        float acc = sg2b[c];
        #pragma unroll
        for (int o = 0; o < C2; ++o) acc += sfe[n * C2 + o] * sg2[o * C1 + c];
        sfc[NN * C2 + e] = acc;
    }
    __syncthreads();

    // Step 9: h2 = elu(L @ t2) -> sfe[1140..1710)
    for (int e = tid; e < NN * C1; e += 256) {
        int n = e / C1, c = e - n * C1;
        float acc = 0.f;
        for (int m = 0; m < NN; ++m) acc += sA[n * NN + m] * sfc[NN * C2 + m * C1 + c];
        sfe[NN * C2 + e] = elu_f(acc);
    }
    __syncthreads();

    // Step 10: column pooling
    if (tid < C1) {
        const int c = tid;
        float pmax = -INFINITY, rmin = INFINITY, s = 0.f;
        for (int n = 0; n < NN; ++n) {
            float v = sfe[NN * C2 + n * C1 + c];
            pmax = fmaxf(pmax, v);
            rmin = fminf(rmin, 1.f / v);
            s += v;
        }
        float nmax = 1.f / rmin;
        sfeat[c] = (pmax == 0.f) ? nmax : pmax;
        sfeat[C1 + c] = s;
    }
    __syncthreads();

    if (tid == 0) {
        float l0 = sdb[0], l1 = sdb[1];
        #pragma unroll
        for (int j = 0; j < 10; ++j) {
            l0 += sfeat[j] * sdw[j * 2 + 0];
            l1 += sfeat[j] * sdw[j * 2 + 1];
        }
        float mx = fmaxf(l0, l1);
        float e0 = expf(l0 - mx), e1 = expf(l1 - mx);
        float s = e0 + e1;
        out[b * 2 + 0] = e0 / s;
        out[b * 2 + 1] = e1 / s;
    }
}

extern "C" void kernel_launch(void* const* d_in, const int* in_sizes, int n_in,
                              void* d_out, int out_size, void* d_ws, size_t ws_size,
                              hipStream_t stream) {
    const float* x       = (const float*)d_in[0];
    const float* conv1_w = (const float*)d_in[1];
    const float* conv1_b = (const float*)d_in[2];
    const float* ln1_g   = (const float*)d_in[3];
    const float* ln1_b   = (const float*)d_in[4];
    const float* conv2_w = (const float*)d_in[5];
    const float* conv2_b = (const float*)d_in[6];
    const float* ln2_g   = (const float*)d_in[7];
    const float* ln2_b   = (const float*)d_in[8];
    const float* conv3_w = (const float*)d_in[9];
    const float* conv3_b = (const float*)d_in[10];
    const float* ln3_g   = (const float*)d_in[11];
    const float* ln3_b   = (const float*)d_in[12];
    const float* agent_w = (const float*)d_in[13];
    const float* agent_b = (const float*)d_in[14];
    const float* gconv1_w= (const float*)d_in[15];
    const float* gconv1_b= (const float*)d_in[16];
    const float* gconv2_w= (const float*)d_in[17];
    const float* gconv2_b= (const float*)d_in[18];
    const float* dense_w = (const float*)d_in[19];
    const float* dense_b = (const float*)d_in[20];
    const int*   rl      = (const int*)d_in[21];
    float* out = (float*)d_out;

    const int B = in_sizes[0] / (NH * WIN);
    const int nrows = B * NH;
    float* feats = (float*)d_ws;  // B*114*20 floats = 9.34 MB

    dim3 block(256);
    dim3 grid1((nrows + 3) / 4);
    hipLaunchKernelGGL(conv_rows_kernel, grid1, block, 0, stream,
                       x, conv1_w, conv1_b, ln1_g, ln1_b,
                       conv2_w, conv2_b, ln2_g, ln2_b,
                       conv3_w, conv3_b, ln3_g, ln3_b,
                       feats, nrows);

    dim3 grid2(B);
    hipLaunchKernelGGL(graph_kernel, grid2, block, 0, stream,
                       feats, agent_w, agent_b,
                       gconv1_w, gconv1_b, gconv2_w, gconv2_b,
                       dense_w, dense_b, rl, out);
}

// Round 2
// 568.071 us; speedup vs baseline: 3.6135x; 3.6135x over previous
//
#include <hip/hip_runtime.h>
#include <math.h>

#define NH    114
#define WIN   130
#define WO1   66
#define WO2   37
#define C1    5
#define C2    10
#define C3    20
#define K1    65
#define K2    30
#define K3    37
#define NN    114

__device__ __forceinline__ float elu_f(float x) { return x > 0.f ? x : expm1f(x); }

__device__ __forceinline__ void lds_fence() {
    asm volatile("s_waitcnt lgkmcnt(0)" ::: "memory");
}

// ---------------- Kernel 1: conv pipeline, one wave per (b,h) row, no block barriers ----------------
__global__ __launch_bounds__(256, 4) void conv_rows_kernel(
    const float* __restrict__ x,
    const float* __restrict__ w1, const float* __restrict__ b1,
    const float* __restrict__ g1, const float* __restrict__ be1,
    const float* __restrict__ w2, const float* __restrict__ b2,
    const float* __restrict__ g2, const float* __restrict__ be2,
    const float* __restrict__ w3, const float* __restrict__ b3,
    const float* __restrict__ g3, const float* __restrict__ be3,
    float* __restrict__ feats, int nrows)
{
    __shared__ float sxin[4][196];
    __shared__ float ss1[4][C1][68];     // channel-major: stride-1 across lanes
    __shared__ float ss2f[4][376];       // flat [w*10+o]
    __shared__ float spart[4][3][24];
    __shared__ float st[4][20];

    const int tid  = threadIdx.x;
    const int wave = tid >> 6;
    const int lane = tid & 63;
    const int row  = blockIdx.x * 4 + wave;
    if (row >= nrows) return;            // legal: no block-wide barriers below

    // ---- stage x row into LDS (zero-pad tail for the accB trick) ----
    const float* xr = x + (size_t)row * WIN;
    sxin[wave][lane]        = xr[lane];
    sxin[wave][64 + lane]   = xr[64 + lane];
    sxin[wave][128 + lane]  = (lane < WIN - 128) ? xr[128 + lane] : 0.f;  // 128..191
    if (lane < 4) sxin[wave][192 + lane] = 0.f;
    lds_fence();

    // ---- conv1 + LN1 + ELU ----
    // lane computes position w=lane; accB computes w=64+lane (kept only for lane<2)
    {
        float accA[C1], accB[C1];
        #pragma unroll
        for (int c = 0; c < C1; ++c) { float bb = b1[c]; accA[c] = bb; accB[c] = bb; }
        for (int k = 0; k < K1; ++k) {
            float xa = sxin[wave][lane + k];
            float xb = sxin[wave][lane + 64 + k];
            #pragma unroll
            for (int c = 0; c < C1; ++c) {
                float wv = w1[k * C1 + c];        // uniform -> s_load
                accA[c] = fmaf(xa, wv, accA[c]);
                accB[c] = fmaf(xb, wv, accB[c]);
            }
        }
        {
            float m = 0.f;
            #pragma unroll
            for (int c = 0; c < C1; ++c) m += accA[c];
            m *= 0.2f;
            float v = 0.f;
            #pragma unroll
            for (int c = 0; c < C1; ++c) { float d = accA[c] - m; v = fmaf(d, d, v); }
            float inv = rsqrtf(v * 0.2f + 1e-3f);
            #pragma unroll
            for (int c = 0; c < C1; ++c)
                ss1[wave][c][lane] = elu_f((accA[c] - m) * inv * g1[c] + be1[c]);
        }
        if (lane < WO1 - 64) {
            float m = 0.f;
            #pragma unroll
            for (int c = 0; c < C1; ++c) m += accB[c];
            m *= 0.2f;
            float v = 0.f;
            #pragma unroll
            for (int c = 0; c < C1; ++c) { float d = accB[c] - m; v = fmaf(d, d, v); }
            float inv = rsqrtf(v * 0.2f + 1e-3f);
            #pragma unroll
            for (int c = 0; c < C1; ++c)
                ss1[wave][c][64 + lane] = elu_f((accB[c] - m) * inv * g1[c] + be1[c]);
        }
    }
    lds_fence();

    // ---- conv2 + LN2 + ELU (lanes 0..36) ----
    if (lane < WO2) {
        float acc[C2];
        #pragma unroll
        for (int o = 0; o < C2; ++o) acc[o] = b2[o];
        for (int k = 0; k < K2; ++k) {
            float v0 = ss1[wave][0][lane + k];
            float v1 = ss1[wave][1][lane + k];
            float v2 = ss1[wave][2][lane + k];
            float v3 = ss1[wave][3][lane + k];
            float v4 = ss1[wave][4][lane + k];
            const float* wk = w2 + k * (C1 * C2);  // uniform -> s_load
            #pragma unroll
            for (int o = 0; o < C2; ++o) {
                float a = acc[o];
                a = fmaf(v0, wk[o], a);
                a = fmaf(v1, wk[10 + o], a);
                a = fmaf(v2, wk[20 + o], a);
                a = fmaf(v3, wk[30 + o], a);
                a = fmaf(v4, wk[40 + o], a);
                acc[o] = a;
            }
        }
        float m = 0.f;
        #pragma unroll
        for (int o = 0; o < C2; ++o) m += acc[o];
        m *= 0.1f;
        float v = 0.f;
        #pragma unroll
        for (int o = 0; o < C2; ++o) { float d = acc[o] - m; v = fmaf(d, d, v); }
        float inv = rsqrtf(v * 0.1f + 1e-3f);
        #pragma unroll
        for (int o = 0; o < C2; ++o)
            ss2f[wave][lane * C2 + o] = elu_f((acc[o] - m) * inv * g2[o] + be2[o]);
    }
    lds_fence();

    // ---- conv3: 60 lanes, 3-way split over the 370-term dot product ----
    if (lane < 60) {
        const int g  = lane / 20;
        const int c  = lane - g * 20;
        const int j0 = g * 124;
        float p = 0.f;
        for (int t = 0; t < 122; ++t) {
            int j = j0 + t;
            p = fmaf(ss2f[wave][j], w3[j * C3 + c], p);
        }
        if (g < 2) {
            #pragma unroll
            for (int t = 122; t < 124; ++t) {
                int j = j0 + t;
                p = fmaf(ss2f[wave][j], w3[j * C3 + c], p);
            }
        }
        spart[wave][g][c] = p;
    }
    lds_fence();

    float myacc = 0.f;
    if (lane < C3) {
        myacc = spart[wave][0][lane] + spart[wave][1][lane] + spart[wave][2][lane] + b3[lane];
        st[wave][lane] = myacc;
    }
    lds_fence();

    if (lane < C3) {
        float sum = 0.f, sumsq = 0.f;
        #pragma unroll
        for (int q = 0; q < C3; ++q) {
            float v = st[wave][q];
            sum += v;
            sumsq = fmaf(v, v, sumsq);
        }
        float m   = sum * (1.f / C3);
        float var = sumsq * (1.f / C3) - m * m;
        float inv = rsqrtf(var + 1e-3f);
        feats[(size_t)row * C3 + lane] = elu_f((myacc - m) * inv * g3[lane] + be3[lane]);
    }
}

// ---------------- Kernel 2: per-batch graph block (unchanged) ----------------
__global__ __launch_bounds__(256) void graph_kernel(
    const float* __restrict__ feats,
    const float* __restrict__ agent_w, const float* __restrict__ agent_b,
    const float* __restrict__ g1w, const float* __restrict__ g1b,
    const float* __restrict__ g2w, const float* __restrict__ g2b,
    const float* __restrict__ dw, const float* __restrict__ db,
    const int* __restrict__ rlp,
    float* __restrict__ out)
{
    __shared__ float sfe[NN * C3];
    __shared__ float sfc[NN * C3];
    __shared__ float sA[NN * NN];
    __shared__ float snrm[NN], sidx[NN], sdv[NN];
    __shared__ float red[256];
    __shared__ float ssigma;
    __shared__ float sfeat[10];
    __shared__ float sg1[C3 * C2], sg1b[C2], sg2[C2 * C1], sg2b[C1], sdw[20], sdb[2];

    const int tid = threadIdx.x;
    const int b = blockIdx.x;
    const float* F = feats + (size_t)b * (NN * C3);
    const int rl = rlp[0];

    if (tid < C3 * C2) sg1[tid] = g1w[tid];
    if (tid < C2) sg1b[tid] = g1b[tid];
    if (tid < C2 * C1) sg2[tid] = g2w[tid];
    if (tid < C1) sg2b[tid] = g2b[tid];
    if (tid < 20) sdw[tid] = dw[tid];
    if (tid < 2) sdb[tid] = db[tid];

    for (int n = tid; n < NN; n += 256) {
        float f[C3];
        float m = 0.f;
        #pragma unroll
        for (int d = 0; d < C3; ++d) { f[d] = F[n * C3 + d]; m += f[d]; }
        m *= (1.f / C3);
        float nr = 0.f, ag = 0.f;
        #pragma unroll
        for (int d = 0; d < C3; ++d) {
            sfe[n * C3 + d] = f[d];
            float c = f[d] - m;
            sfc[n * C3 + d] = c;
            nr += c * c;
            ag += f[d] * agent_w[d];
        }
        snrm[n] = sqrtf(nr);
        sidx[n] = rl ? (1.f / (1.f + expf(-(ag + agent_b[0])))) : 1.f;
    }
    __syncthreads();

    float psum = 0.f;
    for (int e = tid; e < NN * NN; e += 256) {
        int n = e / NN, m = e - n * NN;
        float dot = 0.f;
        #pragma unroll
        for (int d = 0; d < C3; ++d) dot += sfc[n * C3 + d] * sfc[m * C3 + d];
        float corr = dot / (snrm[n] * snrm[m]);
        float dist = (n == m) ? 0.f : (1.f - corr);
        sA[e] = dist;
        psum += dist;
    }
    red[tid] = psum;
    __syncthreads();
    for (int s = 128; s > 0; s >>= 1) {
        if (tid < s) red[tid] += red[tid + s];
        __syncthreads();
    }
    if (tid == 0) ssigma = red[0] / (float)(NN * NN);
    __syncthreads();

    const float sig = ssigma;
    const float inv2s2 = 1.f / (2.f * sig * sig);
    for (int e = tid; e < NN * NN; e += 256) {
        int n = e / NN, m = e - n * NN;
        float dist = sA[e];
        sA[e] = sidx[n] * sidx[m] * expf(-dist * dist * inv2s2);
    }
    __syncthreads();

    for (int n = tid; n < NN; n += 256) {
        float s = 0.f;
        for (int m = 0; m < NN; ++m) s += sA[n * NN + m];
        float dv = rsqrtf(s);
        if (isinf(dv)) dv = 0.f;
        sdv[n] = dv;
    }
    __syncthreads();

    for (int e = tid; e < NN * NN; e += 256) {
        int n = e / NN, m = e - n * NN;
        sA[e] *= sdv[n] * sdv[m];
    }
    __syncthreads();

    for (int e = tid; e < NN * C2; e += 256) {
        int n = e / C2, o = e - n * C2;
        float acc = 0.f;
        #pragma unroll
        for (int d = 0; d < C3; ++d) acc += sfe[n * C3 + d] * sg1[d * C2 + o];
        sfc[e] = acc * sidx[n] + sg1b[o];
    }
    __syncthreads();

    for (int e = tid; e < NN * C2; e += 256) {
        int n = e / C2, o = e - n * C2;
        float acc = 0.f;
        for (int m = 0; m < NN; ++m) acc += sA[n * NN + m] * sfc[m * C2 + o];
        sfe[e] = elu_f(acc);
    }
    __syncthreads();

    for (int e = tid; e < NN * C1; e += 256) {
        int n = e / C1, c = e - n * C1;
        float acc = sg2b[c];
        #pragma unroll
        for (int o = 0; o < C2; ++o) acc += sfe[n * C2 + o] * sg2[o * C1 + c];
        sfc[NN * C2 + e] = acc;
    }
    __syncthreads();

    for (int e = tid; e < NN * C1; e += 256) {
        int n = e / C1, c = e - n * C1;
        float acc = 0.f;
        for (int m = 0; m < NN; ++m) acc += sA[n * NN + m] * sfc[NN * C2 + m * C1 + c];
        sfe[NN * C2 + e] = elu_f(acc);
    }
    __syncthreads();

    if (tid < C1) {
        const int c = tid;
        float pmax = -INFINITY, rmin = INFINITY, s = 0.f;
        for (int n = 0; n < NN; ++n) {
            float v = sfe[NN * C2 + n * C1 + c];
            pmax = fmaxf(pmax, v);
            rmin = fminf(rmin, 1.f / v);
            s += v;
        }
        float nmax = 1.f / rmin;
        sfeat[c] = (pmax == 0.f) ? nmax : pmax;
        sfeat[C1 + c] = s;
    }
    __syncthreads();

    if (tid == 0) {
        float l0 = sdb[0], l1 = sdb[1];
        #pragma unroll
        for (int j = 0; j < 10; ++j) {
            l0 += sfeat[j] * sdw[j * 2 + 0];
            l1 += sfeat[j] * sdw[j * 2 + 1];
        }
        float mx = fmaxf(l0, l1);
        float e0 = expf(l0 - mx), e1 = expf(l1 - mx);
        float s = e0 + e1;
        out[b * 2 + 0] = e0 / s;
        out[b * 2 + 1] = e1 / s;
    }
}

extern "C" void kernel_launch(void* const* d_in, const int* in_sizes, int n_in,
                              void* d_out, int out_size, void* d_ws, size_t ws_size,
                              hipStream_t stream) {
    const float* x       = (const float*)d_in[0];
    const float* conv1_w = (const float*)d_in[1];
    const float* conv1_b = (const float*)d_in[2];
    const float* ln1_g   = (const float*)d_in[3];
    const float* ln1_b   = (const float*)d_in[4];
    const float* conv2_w = (const float*)d_in[5];
    const float* conv2_b = (const float*)d_in[6];
    const float* ln2_g   = (const float*)d_in[7];
    const float* ln2_b   = (const float*)d_in[8];
    const float* conv3_w = (const float*)d_in[9];
    const float* conv3_b = (const float*)d_in[10];
    const float* ln3_g   = (const float*)d_in[11];
    const float* ln3_b   = (const float*)d_in[12];
    const float* agent_w = (const float*)d_in[13];
    const float* agent_b = (const float*)d_in[14];
    const float* gconv1_w= (const float*)d_in[15];
    const float* gconv1_b= (const float*)d_in[16];
    const float* gconv2_w= (const float*)d_in[17];
    const float* gconv2_b= (const float*)d_in[18];
    const float* dense_w = (const float*)d_in[19];
    const float* dense_b = (const float*)d_in[20];
    const int*   rl      = (const int*)d_in[21];
    float* out = (float*)d_out;

    const int B = in_sizes[0] / (NH * WIN);
    const int nrows = B * NH;
    float* feats = (float*)d_ws;

    dim3 block(256);
    dim3 grid1((nrows + 3) / 4);
    hipLaunchKernelGGL(conv_rows_kernel, grid1, block, 0, stream,
                       x, conv1_w, conv1_b, ln1_g, ln1_b,
                       conv2_w, conv2_b, ln2_g, ln2_b,
                       conv3_w, conv3_b, ln3_g, ln3_b,
                       feats, nrows);

    dim3 grid2(B);
    hipLaunchKernelGGL(graph_kernel, grid2, block, 0, stream,
                       feats, agent_w, agent_b,
                       gconv1_w, gconv1_b, gconv2_w, gconv2_b,
                       dense_w, dense_b, rl, out);
}